// Round 4
// baseline (70126.984 us; speedup 1.0000x reference)
//
#include <hip/hip_runtime.h>
#include <stdint.h>

// EchoStateNetwork MI355X:
//  - 64 independent sequences (b,ch); h_{t+1} = 0.9*tanh(W_in u_t(b) + W_res^T h_t) + 0.1*h_t
//  - Phase A: inp[t][b][k] = u . W_in, stashed into out[b][0][t][k] (consumed then
//    overwritten by the recurrence at exactly step t, same thread, ordered).
//  - Phase B: persistent kernel, 256 blocks = 8 seq-groups x 32 col-blocks.
//    W_res column slice in VGPRs (32 float4/thread).
//    Exchange: single-copy-atomic 8B pairs (value, tag=t+1), double-buffered
//    hbuf[t&1][seq][1024] in d_ws. Fast path sc0 (XCD-local L2, grp = bx&7 ==
//    round-robin XCD id); agent-scope fallback for undefined mappings.
//    NEW (this round):
//    (a) per-thread CONTIGUOUS 256B exchange runs: thread (es,ecol) loads cols
//        [ecol*32, ecol*32+32) of seq bc -> depends on exactly ONE producer
//        block; retry = 256B (one L2 RTT), not 64KB; bulk = 16x dwordx4;
//        LDS staging = 8x ds_write_b128 (was 32 scalar).
//    (b) packed matvec: v_pk_fma_f32 via ext_vector<float,2> elementwise fma
//        (halves VALU issue: 1024 scalar fma -> 512 packed).
//    (c) LDS h double-buffer -> bar3 removed, 2 barriers/step. LDS 107KB.
//    Lapping-safe: producer rewrites a slot (tag+2) only after consuming h(tag+1)
//    from ALL col-blocks incl. this one, which publishes only after its spin
//    exited with vmcnt drained. Deadlock-safe: 256 co-resident blocks
//    (grid == #CU, launch_bounds(256,1)); deadman guards (stale over hang).

#define H_  1024
#define T_  1024
#define B_  16
#define CH_ 4
#define D_  64
#define F_  256   // CH*D

typedef float f32x2 __attribute__((ext_vector_type(2)));
typedef unsigned int u32x4 __attribute__((ext_vector_type(4)));

// ---------------- Phase A: inp GEMM (fp32, LDS tiled 64x64, K=256 in 4 chunks) ---
__global__ __launch_bounds__(256) void inp_gemm(const float* __restrict__ x,
                                                const float* __restrict__ W_in,
                                                float* __restrict__ out)
{
    __shared__ float U[64 * 68];    // [t 64][f 68]  (pad 68 -> conflict-free a reads)
    __shared__ float Wt[64 * 66];   // [f 64][k 66]  (transposed W_in tile)
    const int k0 = blockIdx.x * 64;
    const int t0 = blockIdx.y * 64;
    const int b  = blockIdx.z;
    const int tid = threadIdx.x;
    const int ty = tid >> 4, tx = tid & 15;     // 4x4 outputs per thread

    float4 acc[4];
    acc[0] = float4{0.f,0.f,0.f,0.f}; acc[1] = acc[0]; acc[2] = acc[0]; acc[3] = acc[0];

    for (int fc = 0; fc < 4; ++fc) {            // f-chunk == channel fc
        {   // stage U: thread (t_l, fs): 16 floats of x[b][fc][t0+t_l][fs*16..]
            const int t_l = tid >> 2, fs = tid & 3;
            const float* src = x + ((size_t)(b * CH_ + fc) * T_ + (t0 + t_l)) * D_ + fs * 16;
            float* dst = &U[t_l * 68 + fs * 16];
            #pragma unroll
            for (int q = 0; q < 4; ++q)
                ((float4*)dst)[q] = ((const float4*)src)[q];
        }
        {   // stage Wt (transpose): thread (k_l, fs): W_in[k0+k_l][fc*64 + fs*16..]
            const int k_l = tid >> 2, fs = tid & 3;
            const float* src = W_in + (size_t)(k0 + k_l) * F_ + fc * 64 + fs * 16;
            float4 v[4];
            #pragma unroll
            for (int q = 0; q < 4; ++q) v[q] = ((const float4*)src)[q];
            #pragma unroll
            for (int q = 0; q < 4; ++q) {
                Wt[(fs*16 + q*4 + 0) * 66 + k_l] = v[q].x;
                Wt[(fs*16 + q*4 + 1) * 66 + k_l] = v[q].y;
                Wt[(fs*16 + q*4 + 2) * 66 + k_l] = v[q].z;
                Wt[(fs*16 + q*4 + 3) * 66 + k_l] = v[q].w;
            }
        }
        __syncthreads();
        #pragma unroll 4
        for (int f4 = 0; f4 < 16; ++f4) {
            float4 a[4], bk[4];
            #pragma unroll
            for (int r = 0; r < 4; ++r)  a[r]  = *(const float4*)&U[(ty*4 + r) * 68 + f4*4];
            #pragma unroll
            for (int kk = 0; kk < 4; ++kk) bk[kk] = *(const float4*)&Wt[(f4*4 + kk) * 66 + tx*4];
            #pragma unroll
            for (int r = 0; r < 4; ++r) {
                const float4 av = a[r];
                acc[r].x = fmaf(av.x, bk[0].x, acc[r].x); acc[r].y = fmaf(av.x, bk[0].y, acc[r].y);
                acc[r].z = fmaf(av.x, bk[0].z, acc[r].z); acc[r].w = fmaf(av.x, bk[0].w, acc[r].w);
                acc[r].x = fmaf(av.y, bk[1].x, acc[r].x); acc[r].y = fmaf(av.y, bk[1].y, acc[r].y);
                acc[r].z = fmaf(av.y, bk[1].z, acc[r].z); acc[r].w = fmaf(av.y, bk[1].w, acc[r].w);
                acc[r].x = fmaf(av.z, bk[2].x, acc[r].x); acc[r].y = fmaf(av.z, bk[2].y, acc[r].y);
                acc[r].z = fmaf(av.z, bk[2].z, acc[r].z); acc[r].w = fmaf(av.z, bk[2].w, acc[r].w);
                acc[r].x = fmaf(av.w, bk[3].x, acc[r].x); acc[r].y = fmaf(av.w, bk[3].y, acc[r].y);
                acc[r].z = fmaf(av.w, bk[3].z, acc[r].z); acc[r].w = fmaf(av.w, bk[3].w, acc[r].w);
            }
        }
        __syncthreads();
    }
    // stash inp tile into out[b][0][t0+ty*4+r][k0+tx*4..]
    #pragma unroll
    for (int r = 0; r < 4; ++r) {
        float* dst = out + ((size_t)(b * CH_) * T_ + (t0 + ty*4 + r)) * H_ + k0 + tx*4;
        *(float4*)dst = acc[r];
    }
}

// 16x global_load_dwordx4 sc0 (L1-bypass, XCD-L2 served) of one contiguous 256B
// run (32 tagged pairs) + vmcnt(0). Early-clobber outputs.
#define LOADP16(vv, a0)                                                           \
    asm volatile(                                                                 \
        "global_load_dwordx4 %0, %16, off sc0\n\t"                                \
        "global_load_dwordx4 %1, %16, off offset:16 sc0\n\t"                      \
        "global_load_dwordx4 %2, %16, off offset:32 sc0\n\t"                      \
        "global_load_dwordx4 %3, %16, off offset:48 sc0\n\t"                      \
        "global_load_dwordx4 %4, %16, off offset:64 sc0\n\t"                      \
        "global_load_dwordx4 %5, %16, off offset:80 sc0\n\t"                      \
        "global_load_dwordx4 %6, %16, off offset:96 sc0\n\t"                      \
        "global_load_dwordx4 %7, %16, off offset:112 sc0\n\t"                     \
        "global_load_dwordx4 %8, %16, off offset:128 sc0\n\t"                     \
        "global_load_dwordx4 %9, %16, off offset:144 sc0\n\t"                     \
        "global_load_dwordx4 %10, %16, off offset:160 sc0\n\t"                    \
        "global_load_dwordx4 %11, %16, off offset:176 sc0\n\t"                    \
        "global_load_dwordx4 %12, %16, off offset:192 sc0\n\t"                    \
        "global_load_dwordx4 %13, %16, off offset:208 sc0\n\t"                    \
        "global_load_dwordx4 %14, %16, off offset:224 sc0\n\t"                    \
        "global_load_dwordx4 %15, %16, off offset:240 sc0\n\t"                    \
        "s_waitcnt vmcnt(0)"                                                      \
        : "=&v"(vv[0]),  "=&v"(vv[1]),  "=&v"(vv[2]),  "=&v"(vv[3]),              \
          "=&v"(vv[4]),  "=&v"(vv[5]),  "=&v"(vv[6]),  "=&v"(vv[7]),              \
          "=&v"(vv[8]),  "=&v"(vv[9]),  "=&v"(vv[10]), "=&v"(vv[11]),             \
          "=&v"(vv[12]), "=&v"(vv[13]), "=&v"(vv[14]), "=&v"(vv[15])              \
        : "v"(a0)                                                                 \
        : "memory")

// ---------------- Phase B: persistent recurrence (XCD-L2 tagged exchange) -------
// grid 256 = group(8, low 3 bits = XCD round-robin) x colblock(32). 256 threads.
// thread: kr = tid>>3 (h-range kr*32..+32), cg = tid&7 (4 cols: C0+cg*4..)
// LDS floats: [0,9216) h buf0, [9216,18432) h buf1  (per seq: 32 chunks x 36),
//             [18432,26880) partials [s][kr 32][33].
// hbuf: [2][64 seq][1024] u64 pairs: low32 = f32 bits, high32 = tag (= t+1;
// 0 == never written, memset per launch).
__global__ __launch_bounds__(256, 1) void esn_recur(const float* __restrict__ Wres,
                                                    float* __restrict__ out,
                                                    unsigned long long* __restrict__ hbuf)
{
    __shared__ float smem[26880];
    const int bx  = blockIdx.x;
    const int grp = bx & 7;                 // seq-group == XCD id under round-robin
    const int j   = bx >> 3;                // col-block
    const int C0  = j * 32;
    const int tid = threadIdx.x;
    const int kr  = tid >> 3;               // 0..31
    const int cg  = tid & 7;                // 0..7
    const int es   = tid >> 5;              // seq-local 0..7
    const int ecol = tid & 31;              // 32-wide lane id (col slice / run id)
    const int bc   = grp * 8 + es;
    const size_t seqBase = (size_t)bc * (T_ * H_);
    const size_t inpBase = (size_t)(bc & ~3) * (T_ * H_);   // out[b][0] stash region

    // W_res slice -> registers (one-time, L2-shared across the 8 groups)
    float4 w4[32];
    #pragma unroll
    for (int kk = 0; kk < 32; ++kk)
        w4[kk] = *(const float4*)&Wres[(size_t)(kr * 32 + kk) * H_ + C0 + cg * 4];

    for (int idx = tid; idx < 18432; idx += 256) smem[idx] = 0.f;   // h bufs = 0
    __syncthreads();

    int use_fast = 1;                                // sticky per-thread L2-path
    unsigned long long  pend_pv   = 0;               // deferred agent publish
    unsigned long long* pend_addr = nullptr;

    for (int t = 0; t < T_; ++t) {
        // inp prefetch (same-thread slot, read-before-write, ordered in program)
        const float inp_v = out[inpBase + (size_t)t * H_ + C0 + ecol];
        float* const hreg = smem + (t & 1) * 9216;   // h LDS buffer for this step

        // ---- phase 1: detect + stage h_{t-1} ------------------------------
        if (t > 0) {
            // contiguous run: cols [ecol*32, ecol*32+32) of seq bc -> produced
            // entirely by col-block (grp, j'=ecol): ONE producer per thread.
            const unsigned long long* src =
                hbuf + ((size_t)(((t - 1) & 1) * 64 + bc)) * H_ + ecol * 32;
            const unsigned long long a0 = (unsigned long long)src;
            const unsigned int want = (unsigned int)t;   // tag written at step t-1
            float4 f4[8];                                // extracted values
            bool ok = false;
            if (use_fast) {
                u32x4 vv[16];                            // (val,tag,val,tag) quads
                int spins = 0;
                for (;;) {
                    LOADP16(vv, a0);
                    unsigned int bad = 0u;
                    #pragma unroll
                    for (int i = 0; i < 16; ++i)
                        bad |= (vv[i].y ^ want) | (vv[i].w ^ want);
                    if (!bad) { ok = true; break; }
                    if (++spins >= 4096) break;          // bounded -> agent fallback
                    __builtin_amdgcn_s_sleep(1);
                }
                if (ok) {
                    #pragma unroll
                    for (int k = 0; k < 8; ++k) {
                        f4[k].x = __uint_as_float(vv[2*k+0].x);
                        f4[k].y = __uint_as_float(vv[2*k+0].z);
                        f4[k].z = __uint_as_float(vv[2*k+1].x);
                        f4[k].w = __uint_as_float(vv[2*k+1].z);
                    }
                } else use_fast = 0;                     // mapping not XCD-local
            }
            if (!ok) {                                   // agent-scope fallback (mall)
                unsigned long long tmp[32];
                int guard = 0;
                for (;;) {
                    #pragma unroll
                    for (int i = 0; i < 32; ++i)
                        tmp[i] = __hip_atomic_load(src + i,
                                                   __ATOMIC_RELAXED, __HIP_MEMORY_SCOPE_AGENT);
                    unsigned int b2 = 0u;
                    #pragma unroll
                    for (int i = 0; i < 32; ++i)
                        b2 |= ((unsigned int)(tmp[i] >> 32)) ^ want;
                    if (!b2 || ++guard > (1 << 16)) break;   // deadman: stale over hang
                    __builtin_amdgcn_s_sleep(2);
                }
                #pragma unroll
                for (int k = 0; k < 8; ++k) {
                    f4[k].x = __uint_as_float((unsigned int)tmp[4*k+0]);
                    f4[k].y = __uint_as_float((unsigned int)tmp[4*k+1]);
                    f4[k].z = __uint_as_float((unsigned int)tmp[4*k+2]);
                    f4[k].w = __uint_as_float((unsigned int)tmp[4*k+3]);
                }
            }
            // stage: cols ecol*32+i -> hreg[es*1152 + ecol*36 + i], i=0..31
            // (chunk ecol of the skewed layout; contiguous -> 8x ds_write_b128)
            float* dst = &hreg[es * 1152 + ecol * 36];
            #pragma unroll
            for (int k = 0; k < 8; ++k) ((float4*)dst)[k] = f4[k];
        }
        __syncthreads();   // bar1: h staged

        // deferred agent publish of h_{t-1} pair (for cross-XCD fallback
        // consumers only); single 8B atomic store, ack drains under matvec.
        if (t > 0)
            __hip_atomic_store(pend_addr, pend_pv,
                               __ATOMIC_RELAXED, __HIP_MEMORY_SCOPE_AGENT);

        // ---- phase 2: matvec (packed f32 fma) -----------------------------
        f32x2 acc[8][2];
        #pragma unroll
        for (int s = 0; s < 8; ++s) { acc[s][0] = (f32x2){0.f,0.f}; acc[s][1] = (f32x2){0.f,0.f}; }
        const int hbase = kr * 36;
        #pragma unroll
        for (int c8 = 0; c8 < 8; ++c8) {
            const float4 wv0 = w4[c8*4+0], wv1 = w4[c8*4+1], wv2 = w4[c8*4+2], wv3 = w4[c8*4+3];
            const f32x2 w00 = {wv0.x, wv0.y}, w01 = {wv0.z, wv0.w};
            const f32x2 w10 = {wv1.x, wv1.y}, w11 = {wv1.z, wv1.w};
            const f32x2 w20 = {wv2.x, wv2.y}, w21 = {wv2.z, wv2.w};
            const f32x2 w30 = {wv3.x, wv3.y}, w31 = {wv3.z, wv3.w};
            #pragma unroll
            for (int s = 0; s < 8; ++s) {
                const float4 hv = *(const float4*)&hreg[s * 1152 + hbase + c8 * 4];
                const f32x2 hx = {hv.x, hv.x}, hy = {hv.y, hv.y};
                const f32x2 hz = {hv.z, hv.z}, hw = {hv.w, hv.w};
                acc[s][0] = __builtin_elementwise_fma(hx, w00, acc[s][0]);
                acc[s][1] = __builtin_elementwise_fma(hx, w01, acc[s][1]);
                acc[s][0] = __builtin_elementwise_fma(hy, w10, acc[s][0]);
                acc[s][1] = __builtin_elementwise_fma(hy, w11, acc[s][1]);
                acc[s][0] = __builtin_elementwise_fma(hz, w20, acc[s][0]);
                acc[s][1] = __builtin_elementwise_fma(hz, w21, acc[s][1]);
                acc[s][0] = __builtin_elementwise_fma(hw, w30, acc[s][0]);
                acc[s][1] = __builtin_elementwise_fma(hw, w31, acc[s][1]);
            }
        }
        // partials [s][kr][33] (+33 stride => 2-way max, free)
        #pragma unroll
        for (int s = 0; s < 8; ++s) {
            float* pp = &smem[18432 + s * 1056 + kr * 33 + cg * 4];
            pp[0] = acc[s][0].x; pp[1] = acc[s][0].y; pp[2] = acc[s][1].x; pp[3] = acc[s][1].y;
        }
        __syncthreads();   // bar2: partials visible

        // ---- phase 3: reduce + epilogue + publish -------------------------
        float s0 = 0.f, s1 = 0.f, s2 = 0.f, s3 = 0.f;
        #pragma unroll
        for (int k2 = 0; k2 < 32; k2 += 4) {
            s0 += smem[18432 + es * 1056 + (k2+0) * 33 + ecol];
            s1 += smem[18432 + es * 1056 + (k2+1) * 33 + ecol];
            s2 += smem[18432 + es * 1056 + (k2+2) * 33 + ecol];
            s3 += smem[18432 + es * 1056 + (k2+3) * 33 + ecol];
        }
        const float sum   = (s0 + s1) + (s2 + s3);
        const float h_old = hreg[es * 1152 + j * 36 + ecol];   // this step's buffer
        const float pre = inp_v + sum;
        const float nv  = 0.9f * tanhf(pre) + 0.1f * h_old;

        unsigned long long* paddr = hbuf + ((size_t)((t & 1) * 64 + bc)) * H_ + C0 + ecol;
        const unsigned long long pv =
            ((unsigned long long)(unsigned int)(t + 1) << 32)
            | (unsigned long long)__float_as_uint(nv);
        // fast publish: XCD-L2 (sc0), quick ack; no barrier needed after -- next
        // step's staging writes the OTHER LDS h buffer (bar3 eliminated).
        asm volatile("global_store_dwordx2 %0, %1, off sc0"
                     :: "v"((unsigned long long)paddr), "v"(pv) : "memory");
        out[seqBase + (size_t)t * H_ + C0 + ecol] = nv;
        if (!use_fast)   // full-fallback progress: immediate agent copy too
            __hip_atomic_store(paddr, pv, __ATOMIC_RELAXED, __HIP_MEMORY_SCOPE_AGENT);
        pend_pv = pv; pend_addr = paddr;             // agent copy next phase 2
    }
}

extern "C" void kernel_launch(void* const* d_in, const int* in_sizes, int n_in,
                              void* d_out, int out_size, void* d_ws, size_t ws_size,
                              hipStream_t stream) {
    const float* x    = (const float*)d_in[0];
    const float* W_in = (const float*)d_in[1];
    const float* Wres = (const float*)d_in[2];
    float* out = (float*)d_out;
    unsigned long long* hbuf = (unsigned long long*)d_ws;

    // zero tags (tag 0 == never written this launch); 2 bufs x 64 seq x 1024 x 8B = 1 MB
    hipMemsetAsync(hbuf, 0, 2ull * 64 * 1024 * sizeof(unsigned long long), stream);
    inp_gemm<<<dim3(16, 16, 16), 256, 0, stream>>>(x, W_in, out);
    esn_recur<<<dim3(256), 256, 0, stream>>>(Wres, out, hbuf);
}

// Round 5
// 5776.602 us; speedup vs baseline: 12.1398x; 12.1398x over previous
//
#include <hip/hip_runtime.h>
#include <stdint.h>

// EchoStateNetwork MI355X:
//  - 64 independent sequences (b,ch); h_{t+1} = 0.9*tanh(W_in u_t(b) + W_res^T h_t) + 0.1*h_t
//  - Phase A: inp[t][b][k] = u . W_in, stashed into out[b][0][t][k] (consumed then
//    overwritten by the recurrence at exactly step t, ordered by block barriers).
//  - Phase B: persistent kernel, 256 blocks = 8 seq-groups x 32 col-blocks.
//    W_res column slice in VGPRs (32 float4/thread).
//    Exchange (REVERTED to R3's proven structure after R4 regression): per-thread
//    STRIDED cols q*32+ecol -> every load instruction is wave-coalesced (lanes
//    0..31 read consecutive 8B pairs) on BOTH the sc0 fast path and the agent
//    fallback. R4's contiguous-run remap made each agent load instruction span
//    64 cache lines -> mall meltdown when the fast path sticky-disabled.
//    Tagged pairs (value, tag=t+1), double-buffered hbuf[t&1][seq][1024].
//    Fast path: sc0 (XCD-local L2 under grp = bx&7 round-robin), bounded 64-spin
//    probe, sticky per-thread fallback to agent scope (correct under any
//    block->XCD mapping). Producers publish sc0 always + agent deferred one phase
//    (ack drains under matvec); in fallback mode also agent immediately.
//    NEW kept from R4 (exchange-independent):
//    (a) packed matvec: v_pk_fma_f32 via ext_vector<float,2> fma (1024 scalar
//        fma -> 512 packed, ~-1024 cy issue/step).
//    (b) LDS h double-buffer -> bar3 removed, 2 barriers/step.
//    Lapping-safe: producer rewrites a slot (tag+2) only after consuming all of
//    h(tag+1), which requires every consumer of tag to have advanced.
//    Deadlock-safe: 256 co-resident blocks (grid == #CU, launch_bounds(256,1));
//    deadman guards (stale-read over hang).

#define H_  1024
#define T_  1024
#define B_  16
#define CH_ 4
#define D_  64
#define F_  256   // CH*D

typedef float f32x2 __attribute__((ext_vector_type(2)));

// ---------------- Phase A: inp GEMM (fp32, LDS tiled 64x64, K=256 in 4 chunks) ---
__global__ __launch_bounds__(256) void inp_gemm(const float* __restrict__ x,
                                                const float* __restrict__ W_in,
                                                float* __restrict__ out)
{
    __shared__ float U[64 * 68];    // [t 64][f 68]  (pad 68 -> conflict-free a reads)
    __shared__ float Wt[64 * 66];   // [f 64][k 66]  (transposed W_in tile)
    const int k0 = blockIdx.x * 64;
    const int t0 = blockIdx.y * 64;
    const int b  = blockIdx.z;
    const int tid = threadIdx.x;
    const int ty = tid >> 4, tx = tid & 15;     // 4x4 outputs per thread

    float4 acc[4];
    acc[0] = float4{0.f,0.f,0.f,0.f}; acc[1] = acc[0]; acc[2] = acc[0]; acc[3] = acc[0];

    for (int fc = 0; fc < 4; ++fc) {            // f-chunk == channel fc
        {   // stage U: thread (t_l, fs): 16 floats of x[b][fc][t0+t_l][fs*16..]
            const int t_l = tid >> 2, fs = tid & 3;
            const float* src = x + ((size_t)(b * CH_ + fc) * T_ + (t0 + t_l)) * D_ + fs * 16;
            float* dst = &U[t_l * 68 + fs * 16];
            #pragma unroll
            for (int q = 0; q < 4; ++q)
                ((float4*)dst)[q] = ((const float4*)src)[q];
        }
        {   // stage Wt (transpose): thread (k_l, fs): W_in[k0+k_l][fc*64 + fs*16..]
            const int k_l = tid >> 2, fs = tid & 3;
            const float* src = W_in + (size_t)(k0 + k_l) * F_ + fc * 64 + fs * 16;
            float4 v[4];
            #pragma unroll
            for (int q = 0; q < 4; ++q) v[q] = ((const float4*)src)[q];
            #pragma unroll
            for (int q = 0; q < 4; ++q) {
                Wt[(fs*16 + q*4 + 0) * 66 + k_l] = v[q].x;
                Wt[(fs*16 + q*4 + 1) * 66 + k_l] = v[q].y;
                Wt[(fs*16 + q*4 + 2) * 66 + k_l] = v[q].z;
                Wt[(fs*16 + q*4 + 3) * 66 + k_l] = v[q].w;
            }
        }
        __syncthreads();
        #pragma unroll 4
        for (int f4 = 0; f4 < 16; ++f4) {
            float4 a[4], bk[4];
            #pragma unroll
            for (int r = 0; r < 4; ++r)  a[r]  = *(const float4*)&U[(ty*4 + r) * 68 + f4*4];
            #pragma unroll
            for (int kk = 0; kk < 4; ++kk) bk[kk] = *(const float4*)&Wt[(f4*4 + kk) * 66 + tx*4];
            #pragma unroll
            for (int r = 0; r < 4; ++r) {
                const float4 av = a[r];
                acc[r].x = fmaf(av.x, bk[0].x, acc[r].x); acc[r].y = fmaf(av.x, bk[0].y, acc[r].y);
                acc[r].z = fmaf(av.x, bk[0].z, acc[r].z); acc[r].w = fmaf(av.x, bk[0].w, acc[r].w);
                acc[r].x = fmaf(av.y, bk[1].x, acc[r].x); acc[r].y = fmaf(av.y, bk[1].y, acc[r].y);
                acc[r].z = fmaf(av.y, bk[1].z, acc[r].z); acc[r].w = fmaf(av.y, bk[1].w, acc[r].w);
                acc[r].x = fmaf(av.z, bk[2].x, acc[r].x); acc[r].y = fmaf(av.z, bk[2].y, acc[r].y);
                acc[r].z = fmaf(av.z, bk[2].z, acc[r].z); acc[r].w = fmaf(av.z, bk[2].w, acc[r].w);
                acc[r].x = fmaf(av.w, bk[3].x, acc[r].x); acc[r].y = fmaf(av.w, bk[3].y, acc[r].y);
                acc[r].z = fmaf(av.w, bk[3].z, acc[r].z); acc[r].w = fmaf(av.w, bk[3].w, acc[r].w);
            }
        }
        __syncthreads();
    }
    // stash inp tile into out[b][0][t0+ty*4+r][k0+tx*4..]
    #pragma unroll
    for (int r = 0; r < 4; ++r) {
        float* dst = out + ((size_t)(b * CH_) * T_ + (t0 + ty*4 + r)) * H_ + k0 + tx*4;
        *(float4*)dst = acc[r];
    }
}

// 32x global_load_dwordx2 sc0 (L1-bypass, XCD-L2 served) + vmcnt(0), one batch.
// Per instruction, lanes read CONSECUTIVE 8B pairs (ecol varies per lane) ->
// fully coalesced. Offsets 0..3840 from two bases (13-bit imm limit); outputs
// early-clobber so the allocator can't alias them onto the live address pairs.
#define LOAD32_SC0(v, a0, a1)                                                     \
    asm volatile(                                                                 \
        "global_load_dwordx2 %0, %32, off sc0\n\t"                                \
        "global_load_dwordx2 %1, %32, off offset:256 sc0\n\t"                     \
        "global_load_dwordx2 %2, %32, off offset:512 sc0\n\t"                     \
        "global_load_dwordx2 %3, %32, off offset:768 sc0\n\t"                     \
        "global_load_dwordx2 %4, %32, off offset:1024 sc0\n\t"                    \
        "global_load_dwordx2 %5, %32, off offset:1280 sc0\n\t"                    \
        "global_load_dwordx2 %6, %32, off offset:1536 sc0\n\t"                    \
        "global_load_dwordx2 %7, %32, off offset:1792 sc0\n\t"                    \
        "global_load_dwordx2 %8, %32, off offset:2048 sc0\n\t"                    \
        "global_load_dwordx2 %9, %32, off offset:2304 sc0\n\t"                    \
        "global_load_dwordx2 %10, %32, off offset:2560 sc0\n\t"                   \
        "global_load_dwordx2 %11, %32, off offset:2816 sc0\n\t"                   \
        "global_load_dwordx2 %12, %32, off offset:3072 sc0\n\t"                   \
        "global_load_dwordx2 %13, %32, off offset:3328 sc0\n\t"                   \
        "global_load_dwordx2 %14, %32, off offset:3584 sc0\n\t"                   \
        "global_load_dwordx2 %15, %32, off offset:3840 sc0\n\t"                   \
        "global_load_dwordx2 %16, %33, off sc0\n\t"                               \
        "global_load_dwordx2 %17, %33, off offset:256 sc0\n\t"                    \
        "global_load_dwordx2 %18, %33, off offset:512 sc0\n\t"                    \
        "global_load_dwordx2 %19, %33, off offset:768 sc0\n\t"                    \
        "global_load_dwordx2 %20, %33, off offset:1024 sc0\n\t"                   \
        "global_load_dwordx2 %21, %33, off offset:1280 sc0\n\t"                   \
        "global_load_dwordx2 %22, %33, off offset:1536 sc0\n\t"                   \
        "global_load_dwordx2 %23, %33, off offset:1792 sc0\n\t"                   \
        "global_load_dwordx2 %24, %33, off offset:2048 sc0\n\t"                   \
        "global_load_dwordx2 %25, %33, off offset:2304 sc0\n\t"                   \
        "global_load_dwordx2 %26, %33, off offset:2560 sc0\n\t"                   \
        "global_load_dwordx2 %27, %33, off offset:2816 sc0\n\t"                   \
        "global_load_dwordx2 %28, %33, off offset:3072 sc0\n\t"                   \
        "global_load_dwordx2 %29, %33, off offset:3328 sc0\n\t"                   \
        "global_load_dwordx2 %30, %33, off offset:3584 sc0\n\t"                   \
        "global_load_dwordx2 %31, %33, off offset:3840 sc0\n\t"                   \
        "s_waitcnt vmcnt(0)"                                                      \
        : "=&v"(v[0]),  "=&v"(v[1]),  "=&v"(v[2]),  "=&v"(v[3]),                  \
          "=&v"(v[4]),  "=&v"(v[5]),  "=&v"(v[6]),  "=&v"(v[7]),                  \
          "=&v"(v[8]),  "=&v"(v[9]),  "=&v"(v[10]), "=&v"(v[11]),                 \
          "=&v"(v[12]), "=&v"(v[13]), "=&v"(v[14]), "=&v"(v[15]),                 \
          "=&v"(v[16]), "=&v"(v[17]), "=&v"(v[18]), "=&v"(v[19]),                 \
          "=&v"(v[20]), "=&v"(v[21]), "=&v"(v[22]), "=&v"(v[23]),                 \
          "=&v"(v[24]), "=&v"(v[25]), "=&v"(v[26]), "=&v"(v[27]),                 \
          "=&v"(v[28]), "=&v"(v[29]), "=&v"(v[30]), "=&v"(v[31])                  \
        : "v"(a0), "v"(a1)                                                        \
        : "memory")

// ---------------- Phase B: persistent recurrence (tagged exchange) --------------
// grid 256 = group(8, low 3 bits = XCD round-robin) x colblock(32). 256 threads.
// thread: kr = tid>>3 (h-range kr*32..+32), cg = tid&7 (4 cols: C0+cg*4..)
// LDS floats: [0,9216) h buf0, [9216,18432) h buf1 (per seq: 32 chunks x 36 skew),
//             [18432,26880) partials [s][kr 32][33].
// hbuf: [2][64 seq][1024] u64 pairs: low32 = f32 bits, high32 = tag (= t+1;
// 0 == never written, memset per launch).
__global__ __launch_bounds__(256, 1) void esn_recur(const float* __restrict__ Wres,
                                                    float* __restrict__ out,
                                                    unsigned long long* __restrict__ hbuf)
{
    __shared__ float smem[26880];
    const int bx  = blockIdx.x;
    const int grp = bx & 7;                 // seq-group == XCD id under round-robin
    const int j   = bx >> 3;                // col-block
    const int C0  = j * 32;
    const int tid = threadIdx.x;
    const int kr  = tid >> 3;               // 0..31
    const int cg  = tid & 7;                // 0..7
    const int es   = tid >> 5;              // seq-local 0..7
    const int ecol = tid & 31;              // col within 32-wide slice
    const int bc   = grp * 8 + es;
    const size_t seqBase = (size_t)bc * (T_ * H_);
    const size_t inpBase = (size_t)(bc & ~3) * (T_ * H_);   // out[b][0] stash region

    // W_res slice -> registers (one-time, L2-shared across the 8 groups)
    float4 w4[32];
    #pragma unroll
    for (int kk = 0; kk < 32; ++kk)
        w4[kk] = *(const float4*)&Wres[(size_t)(kr * 32 + kk) * H_ + C0 + cg * 4];

    for (int idx = tid; idx < 18432; idx += 256) smem[idx] = 0.f;   // h bufs = 0
    __syncthreads();

    int use_fast = 1;                                // sticky per-thread L2-path
    unsigned long long  pend_pv   = 0;               // deferred agent publish
    unsigned long long* pend_addr = nullptr;

    for (int t = 0; t < T_; ++t) {
        // inp prefetch (read-before-write: this row is overwritten by this block
        // only at phase 3 of this step, after bar1/bar2 order the read first)
        const float inp_v = out[inpBase + (size_t)t * H_ + C0 + ecol];
        float* const hreg = smem + (t & 1) * 9216;   // h LDS buffer for this step

        // ---- phase 1: detect + stage h_{t-1} ------------------------------
        if (t > 0) {
            unsigned long long v[32];
            const unsigned long long* src =
                hbuf + ((size_t)(((t - 1) & 1) * 64 + bc)) * H_ + ecol;
            const unsigned long long a0 = (unsigned long long)src;
            const unsigned long long a1 = a0 + 4096;
            const unsigned int want = (unsigned int)t;   // tag written at step t-1
            unsigned int bad = 1u;
            if (use_fast) {
                int spins = 0;
                for (;;) {
                    LOAD32_SC0(v, a0, a1);
                    bad = 0u;
                    #pragma unroll
                    for (int q = 0; q < 32; ++q)
                        bad |= ((unsigned int)(v[q] >> 32)) ^ want;
                    if (!bad) break;
                    if (++spins >= 64) break;        // bounded: fall back, stay correct
                    __builtin_amdgcn_s_sleep(1);
                }
                if (bad) use_fast = 0;               // mapping not XCD-local: go agent
            }
            if (bad) {                               // agent-scope fallback (mall)
                int guard = 0;
                for (;;) {
                    #pragma unroll
                    for (int q = 0; q < 32; ++q)
                        v[q] = __hip_atomic_load(src + q * 32,
                                                 __ATOMIC_RELAXED, __HIP_MEMORY_SCOPE_AGENT);
                    unsigned int b2 = 0u;
                    #pragma unroll
                    for (int q = 0; q < 32; ++q)
                        b2 |= ((unsigned int)(v[q] >> 32)) ^ want;
                    if (!b2 || ++guard > (1 << 16)) break;   // deadman: stale over hang
                    __builtin_amdgcn_s_sleep(2);
                }
            }
            float* dst = &hreg[es * 1152 + ecol];
            #pragma unroll
            for (int q = 0; q < 32; ++q)
                dst[q * 36] = __uint_as_float((unsigned int)(v[q] & 0xffffffffu));
        }
        __syncthreads();   // bar1: h staged (also orders partials reuse below)

        // deferred agent publish of h_{t-1}: slow mall ack drains under matvec
        if (t > 0)
            __hip_atomic_store(pend_addr, pend_pv,
                               __ATOMIC_RELAXED, __HIP_MEMORY_SCOPE_AGENT);

        // ---- phase 2: matvec (packed f32 fma) -----------------------------
        f32x2 acc[8][2];
        #pragma unroll
        for (int s = 0; s < 8; ++s) { acc[s][0] = (f32x2){0.f,0.f}; acc[s][1] = (f32x2){0.f,0.f}; }
        const int hbase = kr * 36;
        #pragma unroll
        for (int c8 = 0; c8 < 8; ++c8) {
            const float4 wv0 = w4[c8*4+0], wv1 = w4[c8*4+1], wv2 = w4[c8*4+2], wv3 = w4[c8*4+3];
            const f32x2 w00 = {wv0.x, wv0.y}, w01 = {wv0.z, wv0.w};
            const f32x2 w10 = {wv1.x, wv1.y}, w11 = {wv1.z, wv1.w};
            const f32x2 w20 = {wv2.x, wv2.y}, w21 = {wv2.z, wv2.w};
            const f32x2 w30 = {wv3.x, wv3.y}, w31 = {wv3.z, wv3.w};
            #pragma unroll
            for (int s = 0; s < 8; ++s) {
                const float4 hv = *(const float4*)&hreg[s * 1152 + hbase + c8 * 4];
                const f32x2 hx = {hv.x, hv.x}, hy = {hv.y, hv.y};
                const f32x2 hz = {hv.z, hv.z}, hw = {hv.w, hv.w};
                acc[s][0] = __builtin_elementwise_fma(hx, w00, acc[s][0]);
                acc[s][1] = __builtin_elementwise_fma(hx, w01, acc[s][1]);
                acc[s][0] = __builtin_elementwise_fma(hy, w10, acc[s][0]);
                acc[s][1] = __builtin_elementwise_fma(hy, w11, acc[s][1]);
                acc[s][0] = __builtin_elementwise_fma(hz, w20, acc[s][0]);
                acc[s][1] = __builtin_elementwise_fma(hz, w21, acc[s][1]);
                acc[s][0] = __builtin_elementwise_fma(hw, w30, acc[s][0]);
                acc[s][1] = __builtin_elementwise_fma(hw, w31, acc[s][1]);
            }
        }
        // partials [s][kr][33] (+33 stride => 2-way max, free)
        #pragma unroll
        for (int s = 0; s < 8; ++s) {
            float* pp = &smem[18432 + s * 1056 + kr * 33 + cg * 4];
            pp[0] = acc[s][0].x; pp[1] = acc[s][0].y; pp[2] = acc[s][1].x; pp[3] = acc[s][1].y;
        }
        __syncthreads();   // bar2: partials visible

        // ---- phase 3: reduce + epilogue + publish -------------------------
        float s0 = 0.f, s1 = 0.f, s2 = 0.f, s3 = 0.f;
        #pragma unroll
        for (int k2 = 0; k2 < 32; k2 += 4) {
            s0 += smem[18432 + es * 1056 + (k2+0) * 33 + ecol];
            s1 += smem[18432 + es * 1056 + (k2+1) * 33 + ecol];
            s2 += smem[18432 + es * 1056 + (k2+2) * 33 + ecol];
            s3 += smem[18432 + es * 1056 + (k2+3) * 33 + ecol];
        }
        const float sum   = (s0 + s1) + (s2 + s3);
        const float h_old = hreg[es * 1152 + j * 36 + ecol];   // this step's buffer
        const float pre = inp_v + sum;
        const float nv  = 0.9f * tanhf(pre) + 0.1f * h_old;

        unsigned long long* paddr = hbuf + ((size_t)((t & 1) * 64 + bc)) * H_ + C0 + ecol;
        const unsigned long long pv =
            ((unsigned long long)(unsigned int)(t + 1) << 32)
            | (unsigned long long)__float_as_uint(nv);
        // fast publish: XCD-L2 (sc0). No bar3: next step's staging writes the
        // OTHER LDS h buffer; bar1 orders partials reuse.
        asm volatile("global_store_dwordx2 %0, %1, off sc0"
                     :: "v"((unsigned long long)paddr), "v"(pv) : "memory");
        out[seqBase + (size_t)t * H_ + C0 + ecol] = nv;
        if (!use_fast)   // fallback-mode progress: immediate agent copy too
            __hip_atomic_store(paddr, pv, __ATOMIC_RELAXED, __HIP_MEMORY_SCOPE_AGENT);
        pend_pv = pv; pend_addr = paddr;             // agent copy next phase 2
    }
}

extern "C" void kernel_launch(void* const* d_in, const int* in_sizes, int n_in,
                              void* d_out, int out_size, void* d_ws, size_t ws_size,
                              hipStream_t stream) {
    const float* x    = (const float*)d_in[0];
    const float* W_in = (const float*)d_in[1];
    const float* Wres = (const float*)d_in[2];
    float* out = (float*)d_out;
    unsigned long long* hbuf = (unsigned long long*)d_ws;

    // zero tags (tag 0 == never written this launch); 2 bufs x 64 seq x 1024 x 8B = 1 MB
    hipMemsetAsync(hbuf, 0, 2ull * 64 * 1024 * sizeof(unsigned long long), stream);
    inp_gemm<<<dim3(16, 16, 16), 256, 0, stream>>>(x, W_in, out);
    esn_recur<<<dim3(256), 256, 0, stream>>>(Wres, out, hbuf);
}